// Round 3
// baseline (204.782 us; speedup 1.0000x reference)
//
#include <hip/hip_runtime.h>

#define NNODES 50000
#define FEAT 256
#define NH 8
#define DHEAD 32
#define DEG 16
#define CDIM 256  // NH*DHEAD

typedef __attribute__((ext_vector_type(4))) float floatx4;
typedef __attribute__((ext_vector_type(8))) short shortx8;
typedef __attribute__((ext_vector_type(8))) unsigned short ushortx8;

__device__ __forceinline__ unsigned short f2bf(float f) {
  union { float f; unsigned u; } v; v.f = f;
  unsigned r = v.u + 0x7fffu + ((v.u >> 16) & 1u);  // RN-even
  return (unsigned short)(r >> 16);
}
__device__ __forceinline__ float bf2f(unsigned short b) {
  union { unsigned u; float f; } v; v.u = ((unsigned)b) << 16;
  return v.f;
}

// Kernel 0: W [H][F][DH] fp32 -> Wt2 bf16 in MFMA-fragment-major order:
// Wt2[((cgrp*8 + kt)*64 + lane)*8 + jj] = element (c = cgrp*16 + (lane&15),
// k = kt*32 + (lane>>4)*8 + jj). Wave B-frag load = one coalesced 1KB load.
__global__ __launch_bounds__(256) void convert_wt(
    const float* __restrict__ W, unsigned short* __restrict__ Wt2) {
  int t = blockIdx.x * 256 + threadIdx.x;
#pragma unroll
  for (int p = 0; p < 4; ++p) {
    int idx = t * 4 + p;  // [0, 65536)
    int jj = idx & 7;
    int l = (idx >> 3) & 63;
    int kt = (idx >> 9) & 7;
    int cgrp = idx >> 12;
    int c = cgrp * 16 + (l & 15);
    int f = kt * 32 + ((l >> 4) << 3) + jj;
    Wt2[idx] = f2bf(W[(size_t)(c >> 5) * (FEAT * DHEAD) + (size_t)f * DHEAD + (c & 31)]);
  }
}

// Kernel 1 (fused): Whb[n][c] = bf16(sum_k h[n][k]*W[c][k] + bW[c]), plus
// s1g[n][h] / s2g[n][h] (s2 includes a_bias) in the epilogue.
// 64x256 tile; A staged to LDS once (fp32->bf16 in regs); barrier-free
// K-loop: A frags via ds_read_b128, B frags direct global->VGPR from
// L2-resident fragment-major Wt2.
__global__ __launch_bounds__(256) void gemm_fused(
    const float* __restrict__ h, const unsigned short* __restrict__ Wt2,
    const float* __restrict__ bW, const float* __restrict__ a_src,
    const float* __restrict__ a_dst, const float* __restrict__ a_bias,
    unsigned short* __restrict__ Whb, float* __restrict__ s1g,
    float* __restrict__ s2g) {
  __shared__ unsigned short As2[8 * 4 * 64 * 8];  // 32 KB, fragment-major
  const int tid = threadIdx.x;
  const int w = tid >> 6, lane = tid & 63;
  const int mrow = lane & 15, quad = lane >> 4;
  const int row0 = blockIdx.x * 64;

  {  // Stage A once: thread covers (row = w*16 + mrow, cols quad*8..+8) x 8 kt
    int grow = row0 + w * 16 + mrow;
    if (grow > NNODES - 1) grow = NNODES - 1;
    const float* hp = h + (size_t)grow * FEAT + quad * 8;
#pragma unroll
    for (int kt = 0; kt < 8; ++kt) {
      float4 v0 = *(const float4*)(hp + kt * 32);
      float4 v1 = *(const float4*)(hp + kt * 32 + 4);
      shortx8 a8;
      a8[0] = (short)f2bf(v0.x); a8[1] = (short)f2bf(v0.y);
      a8[2] = (short)f2bf(v0.z); a8[3] = (short)f2bf(v0.w);
      a8[4] = (short)f2bf(v1.x); a8[5] = (short)f2bf(v1.y);
      a8[6] = (short)f2bf(v1.z); a8[7] = (short)f2bf(v1.w);
      *(shortx8*)&As2[((kt * 4 + w) * 64 + lane) * 8] = a8;
    }
  }
  __syncthreads();

  floatx4 acc[4][4] = {};
#pragma unroll
  for (int kt = 0; kt < 8; ++kt) {
    shortx8 af[4], bfr[4];
#pragma unroll
    for (int ni = 0; ni < 4; ++ni) {
      int cgrp = w * 4 + ni;
      bfr[ni] = *(const shortx8*)&Wt2[((size_t)(cgrp * 8 + kt) * 64 + lane) * 8];
    }
#pragma unroll
    for (int mi = 0; mi < 4; ++mi)
      af[mi] = *(const shortx8*)&As2[((kt * 4 + mi) * 64 + lane) * 8];
#pragma unroll
    for (int mi = 0; mi < 4; ++mi)
#pragma unroll
      for (int ni = 0; ni < 4; ++ni)
        acc[mi][ni] = __builtin_amdgcn_mfma_f32_16x16x32_bf16(
            af[mi], bfr[ni], acc[mi][ni], 0, 0, 0);
  }

  // Epilogue: bias + bf16 store + fused s1/s2 per-head dots.
  // Wave w cols: col = w*64 + ni*16 + mrow; heads h0 = 2w (ni 0,1), h1 = 2w+1.
  float aw_s[4], aw_d[4], bias[4];
#pragma unroll
  for (int ni = 0; ni < 4; ++ni) {
    int col = w * 64 + ni * 16 + mrow;
    aw_s[ni] = a_src[col];
    aw_d[ni] = a_dst[col];
    bias[ni] = bW[col];
  }
  float ab0 = a_bias[w * 2], ab1 = a_bias[w * 2 + 1];
#pragma unroll
  for (int mi = 0; mi < 4; ++mi) {
#pragma unroll
    for (int ni = 0; ni < 4; ++ni) {
      int col = w * 64 + ni * 16 + mrow;
#pragma unroll
      for (int r = 0; r < 4; ++r) {
        int row = row0 + mi * 16 + quad * 4 + r;
        float val = acc[mi][ni][r] + bias[ni];
        acc[mi][ni][r] = val;  // keep fp32 for s1/s2
        if (row < NNODES) Whb[(size_t)row * CDIM + col] = f2bf(val);
      }
    }
#pragma unroll
    for (int r = 0; r < 4; ++r) {
      float s1h0 = acc[mi][0][r] * aw_s[0] + acc[mi][1][r] * aw_s[1];
      float s1h1 = acc[mi][2][r] * aw_s[2] + acc[mi][3][r] * aw_s[3];
      float s2h0 = acc[mi][0][r] * aw_d[0] + acc[mi][1][r] * aw_d[1];
      float s2h1 = acc[mi][2][r] * aw_d[2] + acc[mi][3][r] * aw_d[3];
#pragma unroll
      for (int off = 1; off < 16; off <<= 1) {
        s1h0 += __shfl_xor(s1h0, off, 64);
        s1h1 += __shfl_xor(s1h1, off, 64);
        s2h0 += __shfl_xor(s2h0, off, 64);
        s2h1 += __shfl_xor(s2h1, off, 64);
      }
      if (mrow == 0) {
        int row = row0 + mi * 16 + quad * 4 + r;
        if (row < NNODES) {
          float2 s1v; s1v.x = s1h0; s1v.y = s1h1;
          float2 s2v; s2v.x = s2h0 + ab0; s2v.y = s2h1 + ab1;
          *(float2*)&s1g[(size_t)row * NH + w * 2] = s1v;
          *(float2*)&s2g[(size_t)row * NH + w * 2] = s2v;
        }
      }
    }
  }
}

// Kernel 2: XCD-column-partitioned gather. A (node, column-quarter) pair per
// wave; column quarter q is pinned to XCD pair {2q, 2q+1} via the round-robin
// blockIdx->XCD mapping, so each XCD's compulsory Whb footprint drops from
// 25.6 MB to a 6.4 MB column slice (FETCH_SIZE 206 MB -> ~65 MB target).
// Softmax (cheap, L2-resident operands) is recomputed per quarter.
// Wave-local throughout: no LDS, no barriers.
__global__ __launch_bounds__(256) void aggregate(
    const unsigned short* __restrict__ Whb, const float* __restrict__ s1g,
    const float* __restrict__ s2g, const int* __restrict__ src,
    float* __restrict__ out) {
  const int lane = threadIdx.x & 63;
  const int b = blockIdx.x;
  const int xcd = b & 7;            // round-robin XCD id (perf heuristic only)
  const int q = xcd >> 1;           // column quarter: cols q*64 .. q*64+64
  const int sub = ((b >> 3) << 1) | (xcd & 1);  // node group [0, 12500)
  const int n = sub * 4 + (threadIdx.x >> 6);
  const int rowgrp = lane >> 3;     // which pair of edges this lane gathers
  const int colpart = lane & 7;     // 8-col group within the quarter
  const int hsc = lane & 7;         // head this lane scores
  const int hq = q * 2 + (colpart >> 2);  // head of this lane's accum cols

  // src row: 16 ints (lane&15), L1-broadcast.
  int s0 = src[(size_t)n * DEG + (lane & 15)];
  float s2v = s2g[(size_t)n * NH + hsc];  // a_bias already folded in

  // ---- score-operand gathers (L2-resident s1g) ----
  int se0 = __shfl(s0, lane >> 3);        // src of edge  e  = lane>>3
  int se1 = __shfl(s0, (lane >> 3) + 8);  // src of edge e+8
  float s1a = s1g[(size_t)se0 * NH + hsc];
  float s1b = s1g[(size_t)se1 * NH + hsc];

  // ---- row gathers: 2 x 16B per lane; 8 lanes cover one 256B row slice ----
  int r0 = __shfl(s0, rowgrp);            // edge rowgrp
  int r1 = __shfl(s0, 8 + rowgrp);        // edge rowgrp + 8
  const size_t cbase = (size_t)q * 64 + colpart * 8;
  ushortx8 v0 = *(const ushortx8*)&Whb[(size_t)r0 * CDIM + cbase];
  ushortx8 v1 = *(const ushortx8*)&Whb[(size_t)r1 * CDIM + cbase];

  // ---- wave-parallel softmax over the 16 edges of head hsc ----
  float sc0 = s1a + s2v; sc0 = sc0 > 0.f ? sc0 : 0.2f * sc0;  // leaky relu
  float sc1 = s1b + s2v; sc1 = sc1 > 0.f ? sc1 : 0.2f * sc1;
  float m = fmaxf(sc0, sc1);
  m = fmaxf(m, __shfl_xor(m, 8));
  m = fmaxf(m, __shfl_xor(m, 16));
  m = fmaxf(m, __shfl_xor(m, 32));
  float ex0 = __expf(sc0 - m), ex1 = __expf(sc1 - m);
  float sum = ex0 + ex1;
  sum += __shfl_xor(sum, 8);
  sum += __shfl_xor(sum, 16);
  sum += __shfl_xor(sum, 32);
  float inv = 1.f / sum;
  float w0 = ex0 * inv;  // attn of (edge lane>>3,     head lane&7)
  float w1 = ex1 * inv;  // attn of (edge (lane>>3)+8, head lane&7)

  // ---- weights this lane needs: (e = rowgrp, hq) and (e = rowgrp+8, hq) ----
  float wgt0 = __shfl(w0, rowgrp * 8 + hq);
  float wgt1 = __shfl(w1, rowgrp * 8 + hq);

  // ---- weighted accumulate over this lane's 2 edges, 8 cols ----
  float acc[8];
#pragma unroll
  for (int j = 0; j < 8; ++j)
    acc[j] = wgt0 * bf2f(v0[j]) + wgt1 * bf2f(v1[j]);

  // ---- reduce over the 8 rowgrps (edges) sharing this col group ----
#pragma unroll
  for (int j = 0; j < 8; ++j) {
    acc[j] += __shfl_xor(acc[j], 8);
    acc[j] += __shfl_xor(acc[j], 16);
    acc[j] += __shfl_xor(acc[j], 32);
  }

  // ---- store: rowgrp 0 writes cols [cbase, +4), rowgrp 1 [cbase+4, +4) ----
  if (rowgrp < 2) {
    floatx4 o;
    o.x = rowgrp ? acc[4] : acc[0];
    o.y = rowgrp ? acc[5] : acc[1];
    o.z = rowgrp ? acc[6] : acc[2];
    o.w = rowgrp ? acc[7] : acc[3];
    __builtin_nontemporal_store(
        o, (floatx4*)&out[(size_t)n * CDIM + cbase + rowgrp * 4]);
  }
}

extern "C" void kernel_launch(void* const* d_in, const int* in_sizes, int n_in,
                              void* d_out, int out_size, void* d_ws, size_t ws_size,
                              hipStream_t stream) {
  const float* h = (const float*)d_in[0];
  const float* W = (const float*)d_in[1];
  const float* bW = (const float*)d_in[2];
  const float* a_src = (const float*)d_in[3];
  const float* a_dst = (const float*)d_in[4];
  const float* a_bias = (const float*)d_in[5];
  const int* src = (const int*)d_in[6];
  // d_in[7] (dst) unused: dst = repeat(arange(N), DEG) structurally.
  float* out = (float*)d_out;

  unsigned short* Whb = (unsigned short*)d_ws;          // [N][256] bf16, 25.6 MB
  unsigned short* Wt2 = Whb + (size_t)NNODES * CDIM;    // [256][256] bf16, 131 KB
  float* s1g = (float*)(Wt2 + CDIM * FEAT);             // [N][8] fp32, 1.6 MB
  float* s2g = s1g + (size_t)NNODES * NH;               // [N][8] fp32, 1.6 MB

  convert_wt<<<64, 256, 0, stream>>>(W, Wt2);
  gemm_fused<<<(NNODES + 63) / 64, 256, 0, stream>>>(h, Wt2, bW, a_src, a_dst,
                                                     a_bias, Whb, s1g, s2g);
  // 12500 node-groups x 4 column quarters; 50000 % 8 == 0 so the XCD
  // round-robin is bijective w.r.t. the (quarter, node-group) decomposition.
  aggregate<<<50000, 256, 0, stream>>>(Whb, s1g, s2g, src, out);
}

// Round 4
// 204.150 us; speedup vs baseline: 1.0031x; 1.0031x over previous
//
#include <hip/hip_runtime.h>

#define NNODES 50000
#define FEAT 256
#define NH 8
#define DHEAD 32
#define DEG 16
#define CDIM 256  // NH*DHEAD

typedef __attribute__((ext_vector_type(4))) float floatx4;
typedef __attribute__((ext_vector_type(8))) short shortx8;
typedef __attribute__((ext_vector_type(8))) unsigned short ushortx8;

__device__ __forceinline__ unsigned short f2bf(float f) {
  union { float f; unsigned u; } v; v.f = f;
  unsigned r = v.u + 0x7fffu + ((v.u >> 16) & 1u);  // RN-even
  return (unsigned short)(r >> 16);
}
__device__ __forceinline__ float bf2f(unsigned short b) {
  union { unsigned u; float f; } v; v.u = ((unsigned)b) << 16;
  return v.f;
}

// Kernel 0: W [H][F][DH] fp32 -> Wt2 bf16 in MFMA-fragment-major order:
// Wt2[((cgrp*8 + kt)*64 + lane)*8 + jj] = element (c = cgrp*16 + (lane&15),
// k = kt*32 + (lane>>4)*8 + jj). Wave B-frag load = one coalesced 1KB load.
__global__ __launch_bounds__(256) void convert_wt(
    const float* __restrict__ W, unsigned short* __restrict__ Wt2) {
  int t = blockIdx.x * 256 + threadIdx.x;
#pragma unroll
  for (int p = 0; p < 4; ++p) {
    int idx = t * 4 + p;  // [0, 65536)
    int jj = idx & 7;
    int l = (idx >> 3) & 63;
    int kt = (idx >> 9) & 7;
    int cgrp = idx >> 12;
    int c = cgrp * 16 + (l & 15);
    int f = kt * 32 + ((l >> 4) << 3) + jj;
    Wt2[idx] = f2bf(W[(size_t)(c >> 5) * (FEAT * DHEAD) + (size_t)f * DHEAD + (c & 31)]);
  }
}

// Kernel 1 (fused): Whb (HEAD-MAJOR [H][N][32]) = bf16(h @ W + bW), plus
// s1g[n][h] / s2g[n][h] (s2 includes a_bias) in the epilogue.
// Head-major layout makes each head's slab 3.2 MB contiguous so the
// aggregate's per-XCD working set fits the 4 MB L2 exactly.
__global__ __launch_bounds__(256) void gemm_fused(
    const float* __restrict__ h, const unsigned short* __restrict__ Wt2,
    const float* __restrict__ bW, const float* __restrict__ a_src,
    const float* __restrict__ a_dst, const float* __restrict__ a_bias,
    unsigned short* __restrict__ Whb, float* __restrict__ s1g,
    float* __restrict__ s2g) {
  __shared__ unsigned short As2[8 * 4 * 64 * 8];  // 32 KB, fragment-major
  const int tid = threadIdx.x;
  const int w = tid >> 6, lane = tid & 63;
  const int mrow = lane & 15, quad = lane >> 4;
  const int row0 = blockIdx.x * 64;

  {  // Stage A once: thread covers (row = w*16 + mrow, cols quad*8..+8) x 8 kt
    int grow = row0 + w * 16 + mrow;
    if (grow > NNODES - 1) grow = NNODES - 1;
    const float* hp = h + (size_t)grow * FEAT + quad * 8;
#pragma unroll
    for (int kt = 0; kt < 8; ++kt) {
      float4 v0 = *(const float4*)(hp + kt * 32);
      float4 v1 = *(const float4*)(hp + kt * 32 + 4);
      shortx8 a8;
      a8[0] = (short)f2bf(v0.x); a8[1] = (short)f2bf(v0.y);
      a8[2] = (short)f2bf(v0.z); a8[3] = (short)f2bf(v0.w);
      a8[4] = (short)f2bf(v1.x); a8[5] = (short)f2bf(v1.y);
      a8[6] = (short)f2bf(v1.z); a8[7] = (short)f2bf(v1.w);
      *(shortx8*)&As2[((kt * 4 + w) * 64 + lane) * 8] = a8;
    }
  }
  __syncthreads();

  floatx4 acc[4][4] = {};
#pragma unroll
  for (int kt = 0; kt < 8; ++kt) {
    shortx8 af[4], bfr[4];
#pragma unroll
    for (int ni = 0; ni < 4; ++ni) {
      int cgrp = w * 4 + ni;
      bfr[ni] = *(const shortx8*)&Wt2[((size_t)(cgrp * 8 + kt) * 64 + lane) * 8];
    }
#pragma unroll
    for (int mi = 0; mi < 4; ++mi)
      af[mi] = *(const shortx8*)&As2[((kt * 4 + mi) * 64 + lane) * 8];
#pragma unroll
    for (int mi = 0; mi < 4; ++mi)
#pragma unroll
      for (int ni = 0; ni < 4; ++ni)
        acc[mi][ni] = __builtin_amdgcn_mfma_f32_16x16x32_bf16(
            af[mi], bfr[ni], acc[mi][ni], 0, 0, 0);
  }

  // Epilogue: bias + bf16 store (head-major) + fused s1/s2 per-head dots.
  float aw_s[4], aw_d[4], bias[4];
#pragma unroll
  for (int ni = 0; ni < 4; ++ni) {
    int col = w * 64 + ni * 16 + mrow;
    aw_s[ni] = a_src[col];
    aw_d[ni] = a_dst[col];
    bias[ni] = bW[col];
  }
  float ab0 = a_bias[w * 2], ab1 = a_bias[w * 2 + 1];
#pragma unroll
  for (int mi = 0; mi < 4; ++mi) {
#pragma unroll
    for (int ni = 0; ni < 4; ++ni) {
      int col = w * 64 + ni * 16 + mrow;
      const size_t hbase = (size_t)(col >> 5) * ((size_t)NNODES * 32) + (col & 31);
#pragma unroll
      for (int r = 0; r < 4; ++r) {
        int row = row0 + mi * 16 + quad * 4 + r;
        float val = acc[mi][ni][r] + bias[ni];
        acc[mi][ni][r] = val;  // keep fp32 for s1/s2
        if (row < NNODES) Whb[hbase + (size_t)row * 32] = f2bf(val);
      }
    }
#pragma unroll
    for (int r = 0; r < 4; ++r) {
      float s1h0 = acc[mi][0][r] * aw_s[0] + acc[mi][1][r] * aw_s[1];
      float s1h1 = acc[mi][2][r] * aw_s[2] + acc[mi][3][r] * aw_s[3];
      float s2h0 = acc[mi][0][r] * aw_d[0] + acc[mi][1][r] * aw_d[1];
      float s2h1 = acc[mi][2][r] * aw_d[2] + acc[mi][3][r] * aw_d[3];
#pragma unroll
      for (int off = 1; off < 16; off <<= 1) {
        s1h0 += __shfl_xor(s1h0, off, 64);
        s1h1 += __shfl_xor(s1h1, off, 64);
        s2h0 += __shfl_xor(s2h0, off, 64);
        s2h1 += __shfl_xor(s2h1, off, 64);
      }
      if (mrow == 0) {
        int row = row0 + mi * 16 + quad * 4 + r;
        if (row < NNODES) {
          float2 s1v; s1v.x = s1h0; s1v.y = s1h1;
          float2 s2v; s2v.x = s2h0 + ab0; s2v.y = s2h1 + ab1;
          *(float2*)&s1g[(size_t)row * NH + w * 2] = s1v;
          *(float2*)&s2g[(size_t)row * NH + w * 2] = s2v;
        }
      }
    }
  }
}

// Kernel 2: HEAD-partitioned gather. Block b -> head hh = b&7, pinned to one
// XCD by the round-robin blockIdx->XCD mapping. Per-XCD working set = one
// contiguous head slab of Whb (3.2 MB < 4 MB L2) + s1g (1.6 MB) -> gathers
// are L2 hits after compulsory fill. Softmax per (node,head) computed exactly
// once (head partition = no recompute, unlike the R3 quarter scheme).
// Wave = 4 nodes: score phase (n4 = lane>>4, e = lane&15, one score/lane,
// 4-step shfl_xor softmax); gather phase re-tiles as (n4, e4 = bits2-3,
// c = bits0-1) with 4 serial edges/lane, loads issued before the softmax.
__global__ __launch_bounds__(256) void aggregate(
    const unsigned short* __restrict__ Whb, const float* __restrict__ s1g,
    const float* __restrict__ s2g, const int* __restrict__ src,
    float* __restrict__ out) {
  const int lane = threadIdx.x & 63;
  const int wv = threadIdx.x >> 6;
  const int b = blockIdx.x;
  const int hh = b & 7;                       // head == XCD (perf heuristic)
  const int n = (b >> 3) * 16 + wv * 4 + (lane >> 4);
  const int e16 = lane & 15;

  int s0 = src[(size_t)n * DEG + e16];

  // ---- issue the 4 row-slice gathers early (independent of softmax) ----
  const int c = lane & 3, e4 = (lane >> 2) & 3;
  const unsigned short* Wh = Whb + (size_t)hh * ((size_t)NNODES * 32);
  int rs[4];
#pragma unroll
  for (int k = 0; k < 4; ++k) rs[k] = __shfl(s0, (lane & 48) | (e4 + 4 * k));
  ushortx8 v[4];
#pragma unroll
  for (int k = 0; k < 4; ++k)
    v[k] = *(const ushortx8*)&Wh[(size_t)rs[k] * 32 + c * 8];

  // ---- score + softmax for head hh (one score per lane) ----
  float sc = s1g[(size_t)s0 * NH + hh] + s2g[(size_t)n * NH + hh];
  sc = sc > 0.f ? sc : 0.2f * sc;  // leaky relu (a_bias folded into s2g)
  float m = sc;
  m = fmaxf(m, __shfl_xor(m, 1));
  m = fmaxf(m, __shfl_xor(m, 2));
  m = fmaxf(m, __shfl_xor(m, 4));
  m = fmaxf(m, __shfl_xor(m, 8));
  float ex = __expf(sc - m);
  float sum = ex;
  sum += __shfl_xor(sum, 1);
  sum += __shfl_xor(sum, 2);
  sum += __shfl_xor(sum, 4);
  sum += __shfl_xor(sum, 8);
  float w = ex * (1.f / sum);  // weight of (node n, edge e16, head hh)

  // ---- weighted accumulate: 4 serial edges x 8 cols per lane ----
  float acc[8] = {0.f, 0.f, 0.f, 0.f, 0.f, 0.f, 0.f, 0.f};
#pragma unroll
  for (int k = 0; k < 4; ++k) {
    float wk = __shfl(w, (lane & 48) | (e4 + 4 * k));
    ushortx8 vk = v[k];
#pragma unroll
    for (int j = 0; j < 8; ++j) acc[j] += wk * bf2f(vk[j]);
  }
  // reduce over e4 (lane bits 2,3)
#pragma unroll
  for (int j = 0; j < 8; ++j) {
    acc[j] += __shfl_xor(acc[j], 4);
    acc[j] += __shfl_xor(acc[j], 8);
  }
  if ((lane & 12) == 0) {  // e4 == 0 lanes: write cols hh*32 + c*8 .. +8
    float* op = &out[(size_t)n * CDIM + hh * 32 + c * 8];
    floatx4 o0, o1;
    o0.x = acc[0]; o0.y = acc[1]; o0.z = acc[2]; o0.w = acc[3];
    o1.x = acc[4]; o1.y = acc[5]; o1.z = acc[6]; o1.w = acc[7];
    __builtin_nontemporal_store(o0, (floatx4*)op);
    __builtin_nontemporal_store(o1, (floatx4*)(op + 4));
  }
}

extern "C" void kernel_launch(void* const* d_in, const int* in_sizes, int n_in,
                              void* d_out, int out_size, void* d_ws, size_t ws_size,
                              hipStream_t stream) {
  const float* h = (const float*)d_in[0];
  const float* W = (const float*)d_in[1];
  const float* bW = (const float*)d_in[2];
  const float* a_src = (const float*)d_in[3];
  const float* a_dst = (const float*)d_in[4];
  const float* a_bias = (const float*)d_in[5];
  const int* src = (const int*)d_in[6];
  // d_in[7] (dst) unused: dst = repeat(arange(N), DEG) structurally.
  float* out = (float*)d_out;

  unsigned short* Whb = (unsigned short*)d_ws;          // [8][N][32] bf16, 25.6 MB
  unsigned short* Wt2 = Whb + (size_t)NNODES * CDIM;    // [256][256] bf16, 131 KB
  float* s1g = (float*)(Wt2 + CDIM * FEAT);             // [N][8] fp32, 1.6 MB
  float* s2g = s1g + (size_t)NNODES * NH;               // [N][8] fp32, 1.6 MB

  convert_wt<<<64, 256, 0, stream>>>(W, Wt2);
  gemm_fused<<<(NNODES + 63) / 64, 256, 0, stream>>>(h, Wt2, bW, a_src, a_dst,
                                                     a_bias, Whb, s1g, s2g);
  // 3125 node-groups (16 nodes each) x 8 heads; hh = blockIdx & 7 pins each
  // head's 3.2 MB slab to one XCD's L2.
  aggregate<<<25000, 256, 0, stream>>>(Whb, s1g, s2g, src, out);
}